// Round 6
// baseline (459.592 us; speedup 1.0000x reference)
//
#include <hip/hip_runtime.h>
#include <hip/hip_bf16.h>
#include <cstdint>

// B=8, C=256, H=W=64, N=4096, GROUPS=32
// ws layout: ht(16MB) qb(16MB) kb(16MB) vtb(16MB) wqb/wkb/wvb/wob(4x128KB) gst(2KB) part(16KB)

typedef short short8 __attribute__((ext_vector_type(8)));
typedef float f32x16 __attribute__((ext_vector_type(16)));

__device__ __forceinline__ unsigned short f2bf(float f){
  uint32_t u = __builtin_bit_cast(uint32_t, f);
  u += 0x7FFFu + ((u >> 16) & 1u);   // RNE
  return (unsigned short)(u >> 16);
}
__device__ __forceinline__ uint32_t pk2t(float a, float b){
  // truncating pack: (hi16 of a) | (hi16 of b)<<16
  return (__builtin_bit_cast(uint32_t,a)>>16) | (__builtin_bit_cast(uint32_t,b)&0xFFFF0000u);
}
__device__ __forceinline__ void gload16(const void* g, void* l){
  auto gp = reinterpret_cast<uint32_t __attribute__((address_space(1)))*>(
      reinterpret_cast<uintptr_t>(g));
  auto lp = reinterpret_cast<uint32_t __attribute__((address_space(3)))*>(
      reinterpret_cast<uintptr_t>(l));
  __builtin_amdgcn_global_load_lds(gp, lp, 16, 0, 0);
}
// cross-half (lane^32) scalar reduces — PROVEN construction (rounds 2-3).
// NOTE: do NOT use inline-asm v_permlane32_swap with two same-valued "+v"
// operands: regalloc may coalesce them into one register -> self-swap ->
// returns x[lane^32] instead of the reduce (round 4/5 accuracy bug).
__device__ __forceinline__ float xmax32(float x){ return fmaxf(x, __shfl_xor(x,32)); }
__device__ __forceinline__ float xsum32(float x){ return x + __shfl_xor(x,32); }

// ---------------- weight convert ----------------
__global__ void cvt_w_kernel(const float* wq, const float* wk, const float* wv, const float* wo,
                             ushort* wqb, ushort* wkb, ushort* wvb, ushort* wob){
  int i = blockIdx.x*256 + threadIdx.x;
  wqb[i]=f2bf(wq[i]); wkb[i]=f2bf(wk[i]); wvb[i]=f2bf(wv[i]); wob[i]=f2bf(wo[i]);
}

// ---------------- groupnorm stats: 2048 partial blocks + tiny reduce ----------------
__global__ void gn_stats1_kernel(const float* __restrict__ x, float* __restrict__ part){
  int blk = blockIdx.x;                         // bg = blk>>3, seg = blk&7
  const float* p = x + (size_t)(blk>>3)*32768 + (blk&7)*4096;
  float s=0.f, sq=0.f;
  #pragma unroll
  for(int j=0;j<4;j++){
    float4 v = *reinterpret_cast<const float4*>(p + threadIdx.x*16 + j*4);
    s += v.x+v.y+v.z+v.w;
    sq += v.x*v.x+v.y*v.y+v.z*v.z+v.w*v.w;
  }
  #pragma unroll
  for(int o=32;o>0;o>>=1){ s+=__shfl_down(s,o); sq+=__shfl_down(sq,o); }
  __shared__ float ls[4], lq[4];
  if((threadIdx.x&63)==0){ ls[threadIdx.x>>6]=s; lq[threadIdx.x>>6]=sq; }
  __syncthreads();
  if(threadIdx.x==0){
    part[blk*2]  =ls[0]+ls[1]+ls[2]+ls[3];
    part[blk*2+1]=lq[0]+lq[1]+lq[2]+lq[3];
  }
}
__global__ void gn_stats2_kernel(const float* __restrict__ part, float* __restrict__ gst){
  int bg = threadIdx.x;                         // 256 threads, 1 block
  float s=0.f, sq=0.f;
  #pragma unroll
  for(int j=0;j<8;j++){ s+=part[(bg*8+j)*2]; sq+=part[(bg*8+j)*2+1]; }
  float mu=s*(1.f/32768.f);
  float var=sq*(1.f/32768.f)-mu*mu;
  gst[bg*2]=mu; gst[bg*2+1]=rsqrtf(var+1e-5f);
}

// ---------------- groupnorm apply + transpose to ht[B][N][C] bf16 ----------------
__global__ void gn_apply_kernel(const float* __restrict__ x, const float* __restrict__ gw,
                                const float* __restrict__ gb, const float* __restrict__ gst,
                                ushort* __restrict__ ht){
  int nt=blockIdx.x, ct=blockIdx.y, b=blockIdx.z;
  int n0=nt*64, c0=ct*32;
  __shared__ float tile[32][65];
  __shared__ float smu[4], srs[4], sw[32], sb[32];
  int tid=threadIdx.x;
  if(tid<4){ int g=(c0>>3)+tid; smu[tid]=gst[(b*32+g)*2]; srs[tid]=gst[(b*32+g)*2+1]; }
  if(tid<32){ sw[tid]=gw[c0+tid]; sb[tid]=gb[c0+tid]; }
  __syncthreads();
  int ci=tid>>3, j0=(tid&7)*8;
  const float* xp = x + ((size_t)(b*256)+c0+ci)*4096 + n0 + j0;
  float mu=smu[ci>>3], rs=srs[ci>>3], w=sw[ci], bb=sb[ci];
  float4 va=*reinterpret_cast<const float4*>(xp);
  float4 vb=*reinterpret_cast<const float4*>(xp+4);
  tile[ci][j0+0]=(va.x-mu)*rs*w+bb; tile[ci][j0+1]=(va.y-mu)*rs*w+bb;
  tile[ci][j0+2]=(va.z-mu)*rs*w+bb; tile[ci][j0+3]=(va.w-mu)*rs*w+bb;
  tile[ci][j0+4]=(vb.x-mu)*rs*w+bb; tile[ci][j0+5]=(vb.y-mu)*rs*w+bb;
  tile[ci][j0+6]=(vb.z-mu)*rs*w+bb; tile[ci][j0+7]=(vb.w-mu)*rs*w+bb;
  __syncthreads();
  int nl=tid>>2, oct=tid&3;
  union{ ushort u[8]; uint4 v; } o;
  #pragma unroll
  for(int j=0;j<8;j++) o.u[j]=f2bf(tile[oct*8+j][nl]);
  *reinterpret_cast<uint4*>(ht + ((size_t)(b*4096)+n0+nl)*256 + c0 + oct*8) = o.v;
}

// ---------------- fused Q+K GEMM: shares the A (ht) tile ----------------
__global__ __launch_bounds__(256,2) void gemm_qk(const ushort* __restrict__ A,
         const ushort* __restrict__ Bq, const ushort* __restrict__ Bk,
         ushort* __restrict__ Dq, ushort* __restrict__ Dk,
         const float* __restrict__ bq, const float* __restrict__ bk, float qscale){
  __shared__ ushort Al[128*64];
  __shared__ ushort Bql[128*64];
  __shared__ ushort Bkl[128*64];
  int m0=blockIdx.x*128, n0=blockIdx.y*128;
  int tid=threadIdx.x, w=tid>>6, lane=tid&63, ln=lane&31, hi=lane>>5;
  f32x16 aq[2][2], ak[2][2];
  #pragma unroll
  for(int a=0;a<2;a++)
    #pragma unroll
    for(int c=0;c<2;c++)
      #pragma unroll
      for(int r=0;r<16;r++){ aq[a][c][r]=0.f; ak[a][c][r]=0.f; }
  for(int kt=0;kt<4;kt++){
    __syncthreads();
    #pragma unroll
    for(int i=0;i<4;i++){
      int idx=i*256+tid; int row=idx>>3; int chs=(idx^row)&7;
      gload16(A  + (size_t)(m0+row)*256 + kt*64 + chs*8, (char*)Al  + (i*256+w*64)*16);
    }
    #pragma unroll
    for(int i=0;i<4;i++){
      int idx=i*256+tid; int row=idx>>3; int chs=(idx^row)&7;
      gload16(Bq + (size_t)(n0+row)*256 + kt*64 + chs*8, (char*)Bql + (i*256+w*64)*16);
    }
    #pragma unroll
    for(int i=0;i<4;i++){
      int idx=i*256+tid; int row=idx>>3; int chs=(idx^row)&7;
      gload16(Bk + (size_t)(n0+row)*256 + kt*64 + chs*8, (char*)Bkl + (i*256+w*64)*16);
    }
    __syncthreads();
    #pragma unroll
    for(int kk=0;kk<4;kk++){
      short8 af[2], bqf[2], bkf[2];
      #pragma unroll
      for(int t=0;t<2;t++){
        int ra=(w>>1)*64+t*32+ln; int ca=((kk*2+hi)^ra)&7;
        af[t]=*reinterpret_cast<const short8*>(Al + ra*64 + ca*8);
        int rb=(w&1)*64+t*32+ln; int cb=((kk*2+hi)^rb)&7;
        bqf[t]=*reinterpret_cast<const short8*>(Bql + rb*64 + cb*8);
        bkf[t]=*reinterpret_cast<const short8*>(Bkl + rb*64 + cb*8);
      }
      #pragma unroll
      for(int ti=0;ti<2;ti++)
        #pragma unroll
        for(int tj=0;tj<2;tj++){
          aq[ti][tj]=__builtin_amdgcn_mfma_f32_32x32x16_bf16(af[ti],bqf[tj],aq[ti][tj],0,0,0);
          ak[ti][tj]=__builtin_amdgcn_mfma_f32_32x32x16_bf16(af[ti],bkf[tj],ak[ti][tj],0,0,0);
        }
    }
  }
  #pragma unroll
  for(int ti=0;ti<2;ti++){
    #pragma unroll
    for(int tj=0;tj<2;tj++){
      int col=n0+(w&1)*64+tj*32+ln;
      float bqc=bq[col], bkc=bk[col];
      #pragma unroll
      for(int r=0;r<16;r++){
        int row=m0+(w>>1)*64+ti*32+(r&3)+8*(r>>2)+4*hi;
        Dq[(size_t)row*256+col]=f2bf((aq[ti][tj][r]+bqc)*qscale);
        Dk[(size_t)row*256+col]=f2bf(ak[ti][tj][r]+bkc);
      }
    }
  }
}

// ---------------- V^T GEMM (wv as A-operand): D[c][tok] ----------------
__global__ __launch_bounds__(256,2) void gemm_vt(const ushort* __restrict__ A, const ushort* __restrict__ Bm,
         ushort* __restrict__ D, const float* __restrict__ bias){
  __shared__ ushort Al[128*64];
  __shared__ ushort Bl[128*64];
  int m0=blockIdx.x*128, n0=blockIdx.y*128;
  int tid=threadIdx.x, w=tid>>6, lane=tid&63, ln=lane&31, hi=lane>>5;
  f32x16 acc[2][2];
  #pragma unroll
  for(int a=0;a<2;a++)
    #pragma unroll
    for(int c=0;c<2;c++)
      #pragma unroll
      for(int r=0;r<16;r++) acc[a][c][r]=0.f;
  for(int kt=0;kt<4;kt++){
    __syncthreads();
    #pragma unroll
    for(int i=0;i<4;i++){
      int idx=i*256+tid; int row=idx>>3; int chs=(idx^row)&7;
      gload16(A + (size_t)(m0+row)*256 + kt*64 + chs*8, (char*)Al + (i*256+w*64)*16);
    }
    #pragma unroll
    for(int i=0;i<4;i++){
      int idx=i*256+tid; int row=idx>>3; int chs=(idx^row)&7;
      gload16(Bm + (size_t)(n0+row)*256 + kt*64 + chs*8, (char*)Bl + (i*256+w*64)*16);
    }
    __syncthreads();
    #pragma unroll
    for(int kk=0;kk<4;kk++){
      short8 af[2], bfr[2];
      #pragma unroll
      for(int t=0;t<2;t++){
        int ra=(w>>1)*64+t*32+ln; int ca=((kk*2+hi)^ra)&7;
        af[t]=*reinterpret_cast<const short8*>(Al + ra*64 + ca*8);
        int rb=(w&1)*64+t*32+ln; int cb=((kk*2+hi)^rb)&7;
        bfr[t]=*reinterpret_cast<const short8*>(Bl + rb*64 + cb*8);
      }
      #pragma unroll
      for(int ti=0;ti<2;ti++)
        #pragma unroll
        for(int tj=0;tj<2;tj++)
          acc[ti][tj]=__builtin_amdgcn_mfma_f32_32x32x16_bf16(af[ti],bfr[tj],acc[ti][tj],0,0,0);
    }
  }
  #pragma unroll
  for(int ti=0;ti<2;ti++){
    #pragma unroll
    for(int tj=0;tj<2;tj++){
      int col=n0+(w&1)*64+tj*32+ln;
      #pragma unroll
      for(int r=0;r<16;r++){
        int row=m0+(w>>1)*64+ti*32+(r&3)+8*(r>>2)+4*hi;
        D[(size_t)row*32768+col]=f2bf(acc[ti][tj][r]+bias[row]);
      }
    }
  }
}

// ---------------- fused flash attention + output projection + residual ----------------
// grid (32 n-tiles, 8 batch) x 512 threads. wave w: q-group w&3 (32 rows), K-half w>>2.
// Double-buffered staging (counted vmcnt), precomputed ds-address tables (imm offsets),
// shfl_xor for ALL cross-half exchanges (proven), defer-max, exp2 domain.
__global__ __launch_bounds__(512,2) void attn_kernel(
    const ushort* __restrict__ qb, const ushort* __restrict__ kb,
    const ushort* __restrict__ vtb, const ushort* __restrict__ wob,
    const float* __restrict__ bo, const float* __restrict__ x,
    float* __restrict__ out){
  __shared__ ushort smem[2][32768];    // [buf][ K 32KB | V 32KB ] = 128KB
  __shared__ float ml[8][2][32];
  float* exch = reinterpret_cast<float*>(&smem[0][0]);   // 64KB = buf0; last-used buf is 1
  int tid=threadIdx.x, w=tid>>6, lane=tid&63, ln=lane&31, hi=lane>>5;
  int qg=w&3, h=w>>2;
  int b=blockIdx.y, n0=blockIdx.x*128+qg*32;
  int n=n0+ln;
  short8 qf[16];
  {
    const ushort* qrow = qb + ((size_t)(b*4096)+n)*256 + hi*8;
    #pragma unroll
    for(int kc=0;kc<16;kc++) qf[kc]=*reinterpret_cast<const short8*>(qrow+kc*16);
  }
  f32x16 oacc[8];
  #pragma unroll
  for(int i=0;i<8;i++)
    #pragma unroll
    for(int r=0;r<16;r++) oacc[i][r]=0.f;
  float M=-3.0e38f, L=0.f;
  const ushort* kbp = kb + (size_t)b*4096*256;
  const ushort* vbp = vtb + (size_t)b*4096;

  // precomputed LDS read tables (ushort units); inner-loop reads = table + const imm
  int kr=h*32+ln;
  const ushort* kT[2][4];
  const ushort* vT[2][2];
  #pragma unroll
  for(int bb=0;bb<2;bb++){
    #pragma unroll
    for(int q=0;q<4;q++)
      kT[bb][q] = &smem[bb][0] + kr*256 + ((((2*q+hi))^kr)&7)*8;
    #pragma unroll
    for(int ks=0;ks<2;ks++)
      vT[bb][ks] = &smem[bb][16384] + ln*64 + (((h*4+ks*2+hi)^ln)&7)*8;
  }

  auto stage=[&](int t1, int bufi){
    char* Kd=(char*)&smem[bufi][0];
    char* Vd=(char*)&smem[bufi][16384];
    #pragma unroll
    for(int i=0;i<4;i++){
      int idx=i*512+tid; int row=idx>>5, ch=idx&31;
      int chs=(ch&24)|((ch^row)&7);
      gload16(kbp + (size_t)(t1*64+row)*256 + chs*8, Kd + (i*512+w*64)*16);
    }
    #pragma unroll
    for(int i=0;i<4;i++){
      int idx=i*512+tid; int row=idx>>3; int chs=(idx^row)&7;
      gload16(vbp + (size_t)row*32768 + t1*64 + chs*8, Vd + (i*512+w*64)*16);
    }
  };

  stage(0, 0);   // prologue

#define ATTN_STEP(T_, CUR_) {                                                  \
    if((T_)<63){                                                               \
      stage((T_)+1, (CUR_)^1);                                                 \
      asm volatile("s_waitcnt vmcnt(8)" ::: "memory");                         \
    } else {                                                                   \
      asm volatile("s_waitcnt vmcnt(0)" ::: "memory");                         \
    }                                                                          \
    asm volatile("s_barrier" ::: "memory");                                    \
    f32x16 s;                                                                  \
    _Pragma("unroll")                                                          \
    for(int r=0;r<16;r++) s[r]=0.f;                                            \
    _Pragma("unroll")                                                          \
    for(int kc=0;kc<16;kc++){                                                  \
      short8 a=*reinterpret_cast<const short8*>(kT[CUR_][kc&3] + ((2*kc)&24)*8); \
      s=__builtin_amdgcn_mfma_f32_32x32x16_bf16(a,qf[kc],s,0,0,0);             \
    }                                                                          \
    float tmax=fmaxf(fmaxf(fmaxf(s[0],s[1]),fmaxf(s[2],s[3])),                 \
                     fmaxf(fmaxf(s[4],s[5]),fmaxf(s[6],s[7])));                \
    float tmax2=fmaxf(fmaxf(fmaxf(s[8],s[9]),fmaxf(s[10],s[11])),              \
                      fmaxf(fmaxf(s[12],s[13]),fmaxf(s[14],s[15])));           \
    tmax=xmax32(fmaxf(tmax,tmax2));                                            \
    if(__any(tmax > M + 8.f)){                                                 \
      float Mn=fmaxf(M,tmax);                                                  \
      float sc=exp2f(M-Mn);                                                    \
      L*=sc;                                                                   \
      _Pragma("unroll")                                                        \
      for(int i=0;i<8;i++)                                                     \
        _Pragma("unroll")                                                      \
        for(int r=0;r<16;r++) oacc[i][r]*=sc;                                  \
      M=Mn;                                                                    \
    }                                                                          \
    float p[16]; float ts=0.f;                                                 \
    _Pragma("unroll")                                                          \
    for(int r=0;r<16;r++){ p[r]=exp2f(s[r]-M); ts+=p[r]; }                     \
    L+=xsum32(ts);                                                             \
    short8 pa[2];                                                              \
    _Pragma("unroll")                                                          \
    for(int ks=0;ks<2;ks++){                                                   \
      uint32_t c01=pk2t(p[ks*8+0],p[ks*8+1]);                                  \
      uint32_t c23=pk2t(p[ks*8+2],p[ks*8+3]);                                  \
      uint32_t c45=pk2t(p[ks*8+4],p[ks*8+5]);                                  \
      uint32_t c67=pk2t(p[ks*8+6],p[ks*8+7]);                                  \
      uint32_t x01=(uint32_t)__shfl_xor((int)c01,32), x23=(uint32_t)__shfl_xor((int)c23,32); \
      uint32_t x45=(uint32_t)__shfl_xor((int)c45,32), x67=(uint32_t)__shfl_xor((int)c67,32); \
      union{ uint32_t u[4]; short8 v; } r_;                                    \
      r_.u[0]= hi? x45:c01;                                                    \
      r_.u[1]= hi? x67:c23;                                                    \
      r_.u[2]= hi? c45:x01;                                                    \
      r_.u[3]= hi? c67:x23;                                                    \
      pa[ks]=r_.v;                                                             \
    }                                                                          \
    _Pragma("unroll")                                                          \
    for(int ct=0;ct<8;ct++){                                                   \
      _Pragma("unroll")                                                        \
      for(int ks=0;ks<2;ks++){                                                 \
        short8 a=*reinterpret_cast<const short8*>(vT[CUR_][ks] + ct*2048);     \
        oacc[ct]=__builtin_amdgcn_mfma_f32_32x32x16_bf16(a,pa[ks],oacc[ct],0,0,0); \
      }                                                                        \
    }                                                                          \
    asm volatile("s_barrier" ::: "memory");                                    \
  }

  for(int tt=0;tt<32;tt++){
    int t0=tt*2;
    ATTN_STEP(t0, 0);
    ATTN_STEP(t0+1, 1);
  }
#undef ATTN_STEP

  // -------- merge the two K-halves (wave pair w, w^4) --------
  __syncthreads();
  if(hi==0){ ml[w][0][ln]=M; ml[w][1][ln]=L; }
  __syncthreads();
  float Mp=ml[w^4][0][ln], Lp=ml[w^4][1][ln];
  float Mt=fmaxf(M,Mp);
  float fo=exp2f(M-Mt), fpp=exp2f(Mp-Mt);
  float g=fo/(fo*L+fpp*Lp);
  #pragma unroll
  for(int i=0;i<8;i++)
    #pragma unroll
    for(int r=0;r<16;r++) oacc[i][r]*=g;
  short8 obf[16];
  #pragma unroll
  for(int cb=0;cb<4;cb++){
    __syncthreads();
    float* ex=exch + w*2048;
    #pragma unroll
    for(int u=0;u<2;u++){
      int ct=cb*2+u;
      #pragma unroll
      for(int r=0;r<16;r++){
        int cl=u*32+(r&3)+8*(r>>2)+4*hi;
        ex[cl*32+ln]=oacc[ct][r];
      }
    }
    __syncthreads();
    const float* exq=exch + (w^4)*2048;
    #pragma unroll
    for(int u=0;u<2;u++){
      int ct=cb*2+u;
      #pragma unroll
      for(int r=0;r<16;r++){
        int cl=u*32+(r&3)+8*(r>>2)+4*hi;
        oacc[ct][r]+=exq[cl*32+ln];
      }
    }
    #pragma unroll
    for(int kq=0;kq<4;kq++){
      int ct=cb*2+(kq>>1); int rb=(kq&1)*8;
      uint32_t c01=pk2t(oacc[ct][rb+0],oacc[ct][rb+1]);
      uint32_t c23=pk2t(oacc[ct][rb+2],oacc[ct][rb+3]);
      uint32_t c45=pk2t(oacc[ct][rb+4],oacc[ct][rb+5]);
      uint32_t c67=pk2t(oacc[ct][rb+6],oacc[ct][rb+7]);
      uint32_t x01=(uint32_t)__shfl_xor((int)c01,32), x23=(uint32_t)__shfl_xor((int)c23,32);
      uint32_t x45=(uint32_t)__shfl_xor((int)c45,32), x67=(uint32_t)__shfl_xor((int)c67,32);
      union{ uint32_t u[4]; short8 v; } r_;
      r_.u[0]= hi? x45:c01;
      r_.u[1]= hi? x67:c23;
      r_.u[2]= hi? c45:x01;
      r_.u[3]= hi? c67:x23;
      obf[cb*4+kq]=r_.v;
    }
  }
  // -------- fused output projection + bias + residual --------
  #pragma unroll
  for(int cot=0;cot<4;cot++){
    f32x16 d;
    #pragma unroll
    for(int r=0;r<16;r++) d[r]=0.f;
    int coa=h*128+cot*32+ln;
    const ushort* wr=wob+(size_t)coa*256+hi*8;
    #pragma unroll
    for(int kbv=0;kbv<16;kbv++){
      short8 a=*reinterpret_cast<const short8*>(wr+kbv*16);
      d=__builtin_amdgcn_mfma_f32_32x32x16_bf16(a,obf[kbv],d,0,0,0);
    }
    #pragma unroll
    for(int r=0;r<16;r++){
      int co=h*128+cot*32+(r&3)+8*(r>>2)+4*hi;
      size_t oi=((size_t)(b*256)+co)*4096 + n0+ln;
      out[oi]=d[r]+bo[co]+x[oi];
    }
  }
}

extern "C" void kernel_launch(void* const* d_in, const int* in_sizes, int n_in,
                              void* d_out, int out_size, void* d_ws, size_t ws_size,
                              hipStream_t stream){
  const float* x   =(const float*)d_in[0];
  const float* gw  =(const float*)d_in[1];
  const float* gb  =(const float*)d_in[2];
  const float* wq  =(const float*)d_in[3];
  const float* bq  =(const float*)d_in[4];
  const float* wk  =(const float*)d_in[5];
  const float* bk  =(const float*)d_in[6];
  const float* wv  =(const float*)d_in[7];
  const float* bv  =(const float*)d_in[8];
  const float* wo  =(const float*)d_in[9];
  const float* bo  =(const float*)d_in[10];
  float* out=(float*)d_out;
  char* ws=(char*)d_ws;
  const size_t SZ = (size_t)32768*256*2;   // 16MB per bf16 tensor
  ushort* ht =(ushort*)(ws);
  ushort* qb =(ushort*)(ws+SZ);
  ushort* kb2=(ushort*)(ws+2*SZ);
  ushort* vtb=(ushort*)(ws+3*SZ);
  ushort* wqb=(ushort*)(ws+4*SZ);
  ushort* wkb=(ushort*)(ws+4*SZ+131072);
  ushort* wvb=(ushort*)(ws+4*SZ+262144);
  ushort* wob=(ushort*)(ws+4*SZ+393216);
  float*  gst=(float*) (ws+4*SZ+524288);
  float*  part=(float*)(ws+4*SZ+524288+2048);

  cvt_w_kernel<<<256,256,0,stream>>>(wq,wk,wv,wo,wqb,wkb,wvb,wob);
  gn_stats1_kernel<<<2048,256,0,stream>>>(x,part);
  gn_stats2_kernel<<<1,256,0,stream>>>(part,gst);
  gn_apply_kernel<<<dim3(64,8,8),256,0,stream>>>(x,gw,gb,gst,ht);
  // Q/K fused: Q scale = log2(e)/16 (exp2-domain softmax), K scale 1
  gemm_qk<<<dim3(256,2),256,0,stream>>>(ht,wqb,wkb,qb,kb2,bq,bk,0.090168439f);
  gemm_vt<<<dim3(2,256),256,0,stream>>>(wvb,ht,vtb,bv);
  attn_kernel<<<dim3(32,8),512,0,stream>>>(qb,kb2,vtb,wob,bo,x,out);
}

// Round 7
// 342.241 us; speedup vs baseline: 1.3429x; 1.3429x over previous
//
#include <hip/hip_runtime.h>
#include <hip/hip_bf16.h>
#include <cstdint>

// B=8, C=256, H=W=64, N=4096, GROUPS=32
// ws layout: ht(16MB) qb(16MB) kb(16MB) vtb(16MB) wqb/wkb/wvb/wob(4x128KB) gst(2KB) part(16KB)

typedef short short8 __attribute__((ext_vector_type(8)));
typedef float f32x16 __attribute__((ext_vector_type(16)));

__device__ __forceinline__ unsigned short f2bf(float f){
  uint32_t u = __builtin_bit_cast(uint32_t, f);
  u += 0x7FFFu + ((u >> 16) & 1u);   // RNE
  return (unsigned short)(u >> 16);
}
__device__ __forceinline__ uint32_t pk2t(float a, float b){
  // truncating pack: (hi16 of a) | (hi16 of b)<<16
  return (__builtin_bit_cast(uint32_t,a)>>16) | (__builtin_bit_cast(uint32_t,b)&0xFFFF0000u);
}
__device__ __forceinline__ void gload16(const void* g, void* l){
  auto gp = reinterpret_cast<uint32_t __attribute__((address_space(1)))*>(
      reinterpret_cast<uintptr_t>(g));
  auto lp = reinterpret_cast<uint32_t __attribute__((address_space(3)))*>(
      reinterpret_cast<uintptr_t>(l));
  __builtin_amdgcn_global_load_lds(gp, lp, 16, 0, 0);
}
// cross-half (lane^32) scalar reduces — proven construction (rounds 2-3).
__device__ __forceinline__ float xmax32(float x){ return fmaxf(x, __shfl_xor(x,32)); }
__device__ __forceinline__ float xsum32(float x){ return x + __shfl_xor(x,32); }

// ---------------- weight convert ----------------
__global__ void cvt_w_kernel(const float* wq, const float* wk, const float* wv, const float* wo,
                             ushort* wqb, ushort* wkb, ushort* wvb, ushort* wob){
  int i = blockIdx.x*256 + threadIdx.x;
  wqb[i]=f2bf(wq[i]); wkb[i]=f2bf(wk[i]); wvb[i]=f2bf(wv[i]); wob[i]=f2bf(wo[i]);
}

// ---------------- groupnorm stats: 2048 partial blocks + tiny reduce ----------------
__global__ void gn_stats1_kernel(const float* __restrict__ x, float* __restrict__ part){
  int blk = blockIdx.x;                         // bg = blk>>3, seg = blk&7
  const float* p = x + (size_t)(blk>>3)*32768 + (blk&7)*4096;
  float s=0.f, sq=0.f;
  #pragma unroll
  for(int j=0;j<4;j++){
    float4 v = *reinterpret_cast<const float4*>(p + threadIdx.x*16 + j*4);
    s += v.x+v.y+v.z+v.w;
    sq += v.x*v.x+v.y*v.y+v.z*v.z+v.w*v.w;
  }
  #pragma unroll
  for(int o=32;o>0;o>>=1){ s+=__shfl_down(s,o); sq+=__shfl_down(sq,o); }
  __shared__ float ls[4], lq[4];
  if((threadIdx.x&63)==0){ ls[threadIdx.x>>6]=s; lq[threadIdx.x>>6]=sq; }
  __syncthreads();
  if(threadIdx.x==0){
    part[blk*2]  =ls[0]+ls[1]+ls[2]+ls[3];
    part[blk*2+1]=lq[0]+lq[1]+lq[2]+lq[3];
  }
}
__global__ void gn_stats2_kernel(const float* __restrict__ part, float* __restrict__ gst){
  int bg = threadIdx.x;                         // 256 threads, 1 block
  float s=0.f, sq=0.f;
  #pragma unroll
  for(int j=0;j<8;j++){ s+=part[(bg*8+j)*2]; sq+=part[(bg*8+j)*2+1]; }
  float mu=s*(1.f/32768.f);
  float var=sq*(1.f/32768.f)-mu*mu;
  gst[bg*2]=mu; gst[bg*2+1]=rsqrtf(var+1e-5f);
}

// ---------------- groupnorm apply + transpose to ht[B][N][C] bf16 ----------------
__global__ void gn_apply_kernel(const float* __restrict__ x, const float* __restrict__ gw,
                                const float* __restrict__ gb, const float* __restrict__ gst,
                                ushort* __restrict__ ht){
  int nt=blockIdx.x, ct=blockIdx.y, b=blockIdx.z;
  int n0=nt*64, c0=ct*32;
  __shared__ float tile[32][65];
  __shared__ float smu[4], srs[4], sw[32], sb[32];
  int tid=threadIdx.x;
  if(tid<4){ int g=(c0>>3)+tid; smu[tid]=gst[(b*32+g)*2]; srs[tid]=gst[(b*32+g)*2+1]; }
  if(tid<32){ sw[tid]=gw[c0+tid]; sb[tid]=gb[c0+tid]; }
  __syncthreads();
  int ci=tid>>3, j0=(tid&7)*8;
  const float* xp = x + ((size_t)(b*256)+c0+ci)*4096 + n0 + j0;
  float mu=smu[ci>>3], rs=srs[ci>>3], w=sw[ci], bb=sb[ci];
  float4 va=*reinterpret_cast<const float4*>(xp);
  float4 vb=*reinterpret_cast<const float4*>(xp+4);
  tile[ci][j0+0]=(va.x-mu)*rs*w+bb; tile[ci][j0+1]=(va.y-mu)*rs*w+bb;
  tile[ci][j0+2]=(va.z-mu)*rs*w+bb; tile[ci][j0+3]=(va.w-mu)*rs*w+bb;
  tile[ci][j0+4]=(vb.x-mu)*rs*w+bb; tile[ci][j0+5]=(vb.y-mu)*rs*w+bb;
  tile[ci][j0+6]=(vb.z-mu)*rs*w+bb; tile[ci][j0+7]=(vb.w-mu)*rs*w+bb;
  __syncthreads();
  int nl=tid>>2, oct=tid&3;
  union{ ushort u[8]; uint4 v; } o;
  #pragma unroll
  for(int j=0;j<8;j++) o.u[j]=f2bf(tile[oct*8+j][nl]);
  *reinterpret_cast<uint4*>(ht + ((size_t)(b*4096)+n0+nl)*256 + c0 + oct*8) = o.v;
}

// ---------------- fused Q+K GEMM: shares the A (ht) tile ----------------
__global__ __launch_bounds__(256,2) void gemm_qk(const ushort* __restrict__ A,
         const ushort* __restrict__ Bq, const ushort* __restrict__ Bk,
         ushort* __restrict__ Dq, ushort* __restrict__ Dk,
         const float* __restrict__ bq, const float* __restrict__ bk, float qscale){
  __shared__ ushort Al[128*64];
  __shared__ ushort Bql[128*64];
  __shared__ ushort Bkl[128*64];
  int m0=blockIdx.x*128, n0=blockIdx.y*128;
  int tid=threadIdx.x, w=tid>>6, lane=tid&63, ln=lane&31, hi=lane>>5;
  f32x16 aq[2][2], ak[2][2];
  #pragma unroll
  for(int a=0;a<2;a++)
    #pragma unroll
    for(int c=0;c<2;c++)
      #pragma unroll
      for(int r=0;r<16;r++){ aq[a][c][r]=0.f; ak[a][c][r]=0.f; }
  for(int kt=0;kt<4;kt++){
    __syncthreads();
    #pragma unroll
    for(int i=0;i<4;i++){
      int idx=i*256+tid; int row=idx>>3; int chs=(idx^row)&7;
      gload16(A  + (size_t)(m0+row)*256 + kt*64 + chs*8, (char*)Al  + (i*256+w*64)*16);
    }
    #pragma unroll
    for(int i=0;i<4;i++){
      int idx=i*256+tid; int row=idx>>3; int chs=(idx^row)&7;
      gload16(Bq + (size_t)(n0+row)*256 + kt*64 + chs*8, (char*)Bql + (i*256+w*64)*16);
    }
    #pragma unroll
    for(int i=0;i<4;i++){
      int idx=i*256+tid; int row=idx>>3; int chs=(idx^row)&7;
      gload16(Bk + (size_t)(n0+row)*256 + kt*64 + chs*8, (char*)Bkl + (i*256+w*64)*16);
    }
    __syncthreads();
    #pragma unroll
    for(int kk=0;kk<4;kk++){
      short8 af[2], bqf[2], bkf[2];
      #pragma unroll
      for(int t=0;t<2;t++){
        int ra=(w>>1)*64+t*32+ln; int ca=((kk*2+hi)^ra)&7;
        af[t]=*reinterpret_cast<const short8*>(Al + ra*64 + ca*8);
        int rb=(w&1)*64+t*32+ln; int cb=((kk*2+hi)^rb)&7;
        bqf[t]=*reinterpret_cast<const short8*>(Bql + rb*64 + cb*8);
        bkf[t]=*reinterpret_cast<const short8*>(Bkl + rb*64 + cb*8);
      }
      #pragma unroll
      for(int ti=0;ti<2;ti++)
        #pragma unroll
        for(int tj=0;tj<2;tj++){
          aq[ti][tj]=__builtin_amdgcn_mfma_f32_32x32x16_bf16(af[ti],bqf[tj],aq[ti][tj],0,0,0);
          ak[ti][tj]=__builtin_amdgcn_mfma_f32_32x32x16_bf16(af[ti],bkf[tj],ak[ti][tj],0,0,0);
        }
    }
  }
  #pragma unroll
  for(int ti=0;ti<2;ti++){
    #pragma unroll
    for(int tj=0;tj<2;tj++){
      int col=n0+(w&1)*64+tj*32+ln;
      float bqc=bq[col], bkc=bk[col];
      #pragma unroll
      for(int r=0;r<16;r++){
        int row=m0+(w>>1)*64+ti*32+(r&3)+8*(r>>2)+4*hi;
        Dq[(size_t)row*256+col]=f2bf((aq[ti][tj][r]+bqc)*qscale);
        Dk[(size_t)row*256+col]=f2bf(ak[ti][tj][r]+bkc);
      }
    }
  }
}

// ---------------- V^T GEMM (wv as A-operand): D[c][tok] ----------------
__global__ __launch_bounds__(256,2) void gemm_vt(const ushort* __restrict__ A, const ushort* __restrict__ Bm,
         ushort* __restrict__ D, const float* __restrict__ bias){
  __shared__ ushort Al[128*64];
  __shared__ ushort Bl[128*64];
  int m0=blockIdx.x*128, n0=blockIdx.y*128;
  int tid=threadIdx.x, w=tid>>6, lane=tid&63, ln=lane&31, hi=lane>>5;
  f32x16 acc[2][2];
  #pragma unroll
  for(int a=0;a<2;a++)
    #pragma unroll
    for(int c=0;c<2;c++)
      #pragma unroll
      for(int r=0;r<16;r++) acc[a][c][r]=0.f;
  for(int kt=0;kt<4;kt++){
    __syncthreads();
    #pragma unroll
    for(int i=0;i<4;i++){
      int idx=i*256+tid; int row=idx>>3; int chs=(idx^row)&7;
      gload16(A + (size_t)(m0+row)*256 + kt*64 + chs*8, (char*)Al + (i*256+w*64)*16);
    }
    #pragma unroll
    for(int i=0;i<4;i++){
      int idx=i*256+tid; int row=idx>>3; int chs=(idx^row)&7;
      gload16(Bm + (size_t)(n0+row)*256 + kt*64 + chs*8, (char*)Bl + (i*256+w*64)*16);
    }
    __syncthreads();
    #pragma unroll
    for(int kk=0;kk<4;kk++){
      short8 af[2], bfr[2];
      #pragma unroll
      for(int t=0;t<2;t++){
        int ra=(w>>1)*64+t*32+ln; int ca=((kk*2+hi)^ra)&7;
        af[t]=*reinterpret_cast<const short8*>(Al + ra*64 + ca*8);
        int rb=(w&1)*64+t*32+ln; int cb=((kk*2+hi)^rb)&7;
        bfr[t]=*reinterpret_cast<const short8*>(Bl + rb*64 + cb*8);
      }
      #pragma unroll
      for(int ti=0;ti<2;ti++)
        #pragma unroll
        for(int tj=0;tj<2;tj++)
          acc[ti][tj]=__builtin_amdgcn_mfma_f32_32x32x16_bf16(af[ti],bfr[tj],acc[ti][tj],0,0,0);
    }
  }
  #pragma unroll
  for(int ti=0;ti<2;ti++){
    #pragma unroll
    for(int tj=0;tj<2;tj++){
      int col=n0+(w&1)*64+tj*32+ln;
      #pragma unroll
      for(int r=0;r<16;r++){
        int row=m0+(w>>1)*64+ti*32+(r&3)+8*(r>>2)+4*hi;
        D[(size_t)row*32768+col]=f2bf(acc[ti][tj][r]+bias[row]);
      }
    }
  }
}

// ---------------- fused flash attention + output projection + residual ----------------
// 512 blocks x 256 threads (4 waves). wave w: q-group w&1 (32 rows), K-half w>>1.
// Single K/V buffers (64KB -> 2 blocks/CU) with SPLIT-PHASE staging:
//   top:    vmcnt(8)=K(t) ready -> barrier -> QK -> barrier(K reads done)
//   mid:    stage K(t+1); softmax (VALU, overlaps V wait); vmcnt(8|0)=V(t) ready -> barrier
//   bottom: PV -> barrier(V reads done); stage V(t+1)
// Invariant at loop top: wave's VMEM queue = [K(t) x8 oldest, V(t) x8] -> vmcnt(8) == K done.
// XCD swizzle: cid=(bid&7)*64+bid>>3 gives each XCD one batch (4MB K+V fits 4MB L2).
__global__ __launch_bounds__(256,2) void attn_kernel(
    const ushort* __restrict__ qb, const ushort* __restrict__ kb,
    const ushort* __restrict__ vtb, const ushort* __restrict__ wob,
    const float* __restrict__ bo, const float* __restrict__ x,
    float* __restrict__ out){
  __shared__ ushort Kl[64*256];        // 32KB
  __shared__ ushort Vl[256*64];        // 32KB
  __shared__ float ml[4][2][32];
  float* exch = reinterpret_cast<float*>(Kl);   // 32KB, used only after loop
  int tid=threadIdx.x, w=tid>>6, lane=tid&63, ln=lane&31, hi=lane>>5;
  int qg=w&1, h=w>>1;
  int bid=blockIdx.x;
  int cid=(bid&7)*64 + (bid>>3);       // XCD-affine remap (512 = 8*64, bijective)
  int b=cid>>6, nt=cid&63;
  int n0=nt*64+qg*32;
  int n=n0+ln;
  short8 qf[16];
  {
    const ushort* qrow = qb + ((size_t)(b*4096)+n)*256 + hi*8;
    #pragma unroll
    for(int kc=0;kc<16;kc++) qf[kc]=*reinterpret_cast<const short8*>(qrow+kc*16);
  }
  f32x16 oacc[8];
  #pragma unroll
  for(int i=0;i<8;i++)
    #pragma unroll
    for(int r=0;r<16;r++) oacc[i][r]=0.f;
  float M=-3.0e38f, L=0.f;
  const ushort* kbp = kb + (size_t)b*4096*256;
  const ushort* vbp = vtb + (size_t)b*4096;

  auto stageK=[&](int t1){
    #pragma unroll
    for(int i=0;i<8;i++){
      int idx=i*256+tid; int row=idx>>5, ch=idx&31;
      int chs=(ch&24)|((ch^row)&7);
      gload16(kbp + (size_t)(t1*64+row)*256 + chs*8, (char*)Kl + (i*256+w*64)*16);
    }
  };
  auto stageV=[&](int t1){
    #pragma unroll
    for(int i=0;i<8;i++){
      int idx=i*256+tid; int row=idx>>3; int chs=(idx^row)&7;
      gload16(vbp + (size_t)row*32768 + t1*64 + chs*8, (char*)Vl + (i*256+w*64)*16);
    }
  };

  stageK(0); stageV(0);   // prologue: queue = [K0 x8, V0 x8]

  for(int t=0;t<64;t++){
    asm volatile("s_waitcnt vmcnt(8)" ::: "memory");    // K(t) done
    asm volatile("s_barrier" ::: "memory");             // K(t) visible to all
    // S^T[m][n] = K x Q (swapped): softmax over m is lane-local; log2 domain
    f32x16 s;
    #pragma unroll
    for(int r=0;r<16;r++) s[r]=0.f;
    int kr=h*32+ln;
    const ushort* klr = Kl + kr*256;
    #pragma unroll
    for(int kc=0;kc<16;kc++){
      int cw=kc*2+hi; int chs=(cw&24)|((cw^kr)&7);
      short8 a=*reinterpret_cast<const short8*>(klr+chs*8);
      s=__builtin_amdgcn_mfma_f32_32x32x16_bf16(a,qf[kc],s,0,0,0);
    }
    asm volatile("s_barrier" ::: "memory");             // all waves done reading K(t)
    if(t<63) stageK(t+1);                               // lands during softmax+PV
    float tmax=fmaxf(fmaxf(fmaxf(s[0],s[1]),fmaxf(s[2],s[3])),
                     fmaxf(fmaxf(s[4],s[5]),fmaxf(s[6],s[7])));
    float tmax2=fmaxf(fmaxf(fmaxf(s[8],s[9]),fmaxf(s[10],s[11])),
                      fmaxf(fmaxf(s[12],s[13]),fmaxf(s[14],s[15])));
    tmax=xmax32(fmaxf(tmax,tmax2));
    if(__any(tmax > M + 8.f)){          // defer-max: P bounded by 2^8
      float Mn=fmaxf(M,tmax);
      float sc=exp2f(M-Mn);
      L*=sc;
      #pragma unroll
      for(int i=0;i<8;i++)
        #pragma unroll
        for(int r=0;r<16;r++) oacc[i][r]*=sc;
      M=Mn;
    }
    float p[16]; float ts=0.f;
    #pragma unroll
    for(int r=0;r<16;r++){ p[r]=exp2f(s[r]-M); ts+=p[r]; }
    L+=xsum32(ts);
    // P -> B-operand frags [m=hi*8+e][n=ln]
    short8 pa[2];
    #pragma unroll
    for(int ks=0;ks<2;ks++){
      uint32_t c01=pk2t(p[ks*8+0],p[ks*8+1]);
      uint32_t c23=pk2t(p[ks*8+2],p[ks*8+3]);
      uint32_t c45=pk2t(p[ks*8+4],p[ks*8+5]);
      uint32_t c67=pk2t(p[ks*8+6],p[ks*8+7]);
      uint32_t x01=(uint32_t)__shfl_xor((int)c01,32), x23=(uint32_t)__shfl_xor((int)c23,32);
      uint32_t x45=(uint32_t)__shfl_xor((int)c45,32), x67=(uint32_t)__shfl_xor((int)c67,32);
      union{ uint32_t u[4]; short8 v; } r_;
      r_.u[0]= hi? x45:c01;
      r_.u[1]= hi? x67:c23;
      r_.u[2]= hi? c45:x01;
      r_.u[3]= hi? c67:x23;
      pa[ks]=r_.v;
    }
    if(t<63){ asm volatile("s_waitcnt vmcnt(8)" ::: "memory"); }  // V(t) done (K(t+1) in flight)
    else    { asm volatile("s_waitcnt vmcnt(0)" ::: "memory"); }
    asm volatile("s_barrier" ::: "memory");             // V(t) visible to all
    // O^T[c][n] += V^T x P
    #pragma unroll
    for(int ct=0;ct<8;ct++){
      int c=ct*32+ln;
      const ushort* vlr = Vl + c*64;
      #pragma unroll
      for(int ks=0;ks<2;ks++){
        int cw=h*4+ks*2+hi; int chs=cw^(c&7);
        short8 a=*reinterpret_cast<const short8*>(vlr+chs*8);
        oacc[ct]=__builtin_amdgcn_mfma_f32_32x32x16_bf16(a,pa[ks],oacc[ct],0,0,0);
      }
    }
    asm volatile("s_barrier" ::: "memory");             // all waves done reading V(t)
    if(t<63) stageV(t+1);                               // lands during next QK
  }
  // -------- merge the two K-halves (wave pair w, w^2) --------
  __syncthreads();
  if(hi==0){ ml[w][0][ln]=M; ml[w][1][ln]=L; }
  __syncthreads();
  float Mp=ml[w^2][0][ln], Lp=ml[w^2][1][ln];
  float Mt=fmaxf(M,Mp);
  float fo=exp2f(M-Mt), fpp=exp2f(Mp-Mt);
  float g=fo/(fo*L+fpp*Lp);
  #pragma unroll
  for(int i=0;i<8;i++)
    #pragma unroll
    for(int r=0;r<16;r++) oacc[i][r]*=g;
  short8 obf[16];
  #pragma unroll
  for(int cb=0;cb<4;cb++){
    __syncthreads();
    float* ex=exch + w*2048;
    #pragma unroll
    for(int u=0;u<2;u++){
      int ct=cb*2+u;
      #pragma unroll
      for(int r=0;r<16;r++){
        int cl=u*32+(r&3)+8*(r>>2)+4*hi;
        ex[cl*32+ln]=oacc[ct][r];
      }
    }
    __syncthreads();
    const float* exq=exch + (w^2)*2048;
    #pragma unroll
    for(int u=0;u<2;u++){
      int ct=cb*2+u;
      #pragma unroll
      for(int r=0;r<16;r++){
        int cl=u*32+(r&3)+8*(r>>2)+4*hi;
        oacc[ct][r]+=exq[cl*32+ln];
      }
    }
    #pragma unroll
    for(int kq=0;kq<4;kq++){
      int ct=cb*2+(kq>>1); int rb=(kq&1)*8;
      uint32_t c01=pk2t(oacc[ct][rb+0],oacc[ct][rb+1]);
      uint32_t c23=pk2t(oacc[ct][rb+2],oacc[ct][rb+3]);
      uint32_t c45=pk2t(oacc[ct][rb+4],oacc[ct][rb+5]);
      uint32_t c67=pk2t(oacc[ct][rb+6],oacc[ct][rb+7]);
      uint32_t x01=(uint32_t)__shfl_xor((int)c01,32), x23=(uint32_t)__shfl_xor((int)c23,32);
      uint32_t x45=(uint32_t)__shfl_xor((int)c45,32), x67=(uint32_t)__shfl_xor((int)c67,32);
      union{ uint32_t u[4]; short8 v; } r_;
      r_.u[0]= hi? x45:c01;
      r_.u[1]= hi? x67:c23;
      r_.u[2]= hi? c45:x01;
      r_.u[3]= hi? c67:x23;
      obf[cb*4+kq]=r_.v;
    }
  }
  // -------- fused output projection + bias + residual --------
  #pragma unroll
  for(int cot=0;cot<4;cot++){
    f32x16 d;
    #pragma unroll
    for(int r=0;r<16;r++) d[r]=0.f;
    int coa=h*128+cot*32+ln;
    const ushort* wr=wob+(size_t)coa*256+hi*8;
    #pragma unroll
    for(int kbv=0;kbv<16;kbv++){
      short8 a=*reinterpret_cast<const short8*>(wr+kbv*16);
      d=__builtin_amdgcn_mfma_f32_32x32x16_bf16(a,obf[kbv],d,0,0,0);
    }
    #pragma unroll
    for(int r=0;r<16;r++){
      int co=h*128+cot*32+(r&3)+8*(r>>2)+4*hi;
      size_t oi=((size_t)(b*256)+co)*4096 + n0+ln;
      out[oi]=d[r]+bo[co]+x[oi];
    }
  }
}

extern "C" void kernel_launch(void* const* d_in, const int* in_sizes, int n_in,
                              void* d_out, int out_size, void* d_ws, size_t ws_size,
                              hipStream_t stream){
  const float* x   =(const float*)d_in[0];
  const float* gw  =(const float*)d_in[1];
  const float* gb  =(const float*)d_in[2];
  const float* wq  =(const float*)d_in[3];
  const float* bq  =(const float*)d_in[4];
  const float* wk  =(const float*)d_in[5];
  const float* bk  =(const float*)d_in[6];
  const float* wv  =(const float*)d_in[7];
  const float* bv  =(const float*)d_in[8];
  const float* wo  =(const float*)d_in[9];
  const float* bo  =(const float*)d_in[10];
  float* out=(float*)d_out;
  char* ws=(char*)d_ws;
  const size_t SZ = (size_t)32768*256*2;   // 16MB per bf16 tensor
  ushort* ht =(ushort*)(ws);
  ushort* qb =(ushort*)(ws+SZ);
  ushort* kb2=(ushort*)(ws+2*SZ);
  ushort* vtb=(ushort*)(ws+3*SZ);
  ushort* wqb=(ushort*)(ws+4*SZ);
  ushort* wkb=(ushort*)(ws+4*SZ+131072);
  ushort* wvb=(ushort*)(ws+4*SZ+262144);
  ushort* wob=(ushort*)(ws+4*SZ+393216);
  float*  gst=(float*) (ws+4*SZ+524288);
  float*  part=(float*)(ws+4*SZ+524288+2048);

  cvt_w_kernel<<<256,256,0,stream>>>(wq,wk,wv,wo,wqb,wkb,wvb,wob);
  gn_stats1_kernel<<<2048,256,0,stream>>>(x,part);
  gn_stats2_kernel<<<1,256,0,stream>>>(part,gst);
  gn_apply_kernel<<<dim3(64,8,8),256,0,stream>>>(x,gw,gb,gst,ht);
  // Q/K fused: Q scale = log2(e)/16 (exp2-domain softmax), K scale 1
  gemm_qk<<<dim3(256,2),256,0,stream>>>(ht,wqb,wkb,qb,kb2,bq,bk,0.090168439f);
  gemm_vt<<<dim3(2,256),256,0,stream>>>(wvb,ht,vtb,bv);
  attn_kernel<<<512,256,0,stream>>>(qb,kb2,vtb,wob,bo,x,out);
}

// Round 8
// 325.029 us; speedup vs baseline: 1.4140x; 1.0530x over previous
//
#include <hip/hip_runtime.h>
#include <hip/hip_bf16.h>
#include <cstdint>

// B=8, C=256, H=W=64, N=4096, GROUPS=32
// ws layout: ht(16MB) qb(16MB) kb(16MB) vtb(16MB) wqb/wkb/wvb/wob(4x128KB) gst(2KB) part(16KB)

typedef short short8 __attribute__((ext_vector_type(8)));
typedef float f32x16 __attribute__((ext_vector_type(16)));

__device__ __forceinline__ unsigned short f2bf(float f){
  uint32_t u = __builtin_bit_cast(uint32_t, f);
  u += 0x7FFFu + ((u >> 16) & 1u);   // RNE
  return (unsigned short)(u >> 16);
}
__device__ __forceinline__ uint32_t pk2t(float a, float b){
  // truncating pack: (hi16 of a) | (hi16 of b)<<16
  return (__builtin_bit_cast(uint32_t,a)>>16) | (__builtin_bit_cast(uint32_t,b)&0xFFFF0000u);
}
__device__ __forceinline__ void gload16(const void* g, void* l){
  auto gp = reinterpret_cast<uint32_t __attribute__((address_space(1)))*>(
      reinterpret_cast<uintptr_t>(g));
  auto lp = reinterpret_cast<uint32_t __attribute__((address_space(3)))*>(
      reinterpret_cast<uintptr_t>(l));
  __builtin_amdgcn_global_load_lds(gp, lp, 16, 0, 0);
}
// cross-half (lane^32) scalar reduces — proven construction (rounds 2-3).
__device__ __forceinline__ float xmax32(float x){ return fmaxf(x, __shfl_xor(x,32)); }
__device__ __forceinline__ float xsum32(float x){ return x + __shfl_xor(x,32); }

// ---------------- weight convert ----------------
__global__ void cvt_w_kernel(const float* wq, const float* wk, const float* wv, const float* wo,
                             ushort* wqb, ushort* wkb, ushort* wvb, ushort* wob){
  int i = blockIdx.x*256 + threadIdx.x;
  wqb[i]=f2bf(wq[i]); wkb[i]=f2bf(wk[i]); wvb[i]=f2bf(wv[i]); wob[i]=f2bf(wo[i]);
}

// ---------------- groupnorm stats: 2048 partial blocks + tiny reduce ----------------
__global__ void gn_stats1_kernel(const float* __restrict__ x, float* __restrict__ part){
  int blk = blockIdx.x;                         // bg = blk>>3, seg = blk&7
  const float* p = x + (size_t)(blk>>3)*32768 + (blk&7)*4096;
  float s=0.f, sq=0.f;
  #pragma unroll
  for(int j=0;j<4;j++){
    float4 v = *reinterpret_cast<const float4*>(p + threadIdx.x*16 + j*4);
    s += v.x+v.y+v.z+v.w;
    sq += v.x*v.x+v.y*v.y+v.z*v.z+v.w*v.w;
  }
  #pragma unroll
  for(int o=32;o>0;o>>=1){ s+=__shfl_down(s,o); sq+=__shfl_down(sq,o); }
  __shared__ float ls[4], lq[4];
  if((threadIdx.x&63)==0){ ls[threadIdx.x>>6]=s; lq[threadIdx.x>>6]=sq; }
  __syncthreads();
  if(threadIdx.x==0){
    part[blk*2]  =ls[0]+ls[1]+ls[2]+ls[3];
    part[blk*2+1]=lq[0]+lq[1]+lq[2]+lq[3];
  }
}
__global__ void gn_stats2_kernel(const float* __restrict__ part, float* __restrict__ gst){
  int bg = threadIdx.x;                         // 256 threads, 1 block
  float s=0.f, sq=0.f;
  #pragma unroll
  for(int j=0;j<8;j++){ s+=part[(bg*8+j)*2]; sq+=part[(bg*8+j)*2+1]; }
  float mu=s*(1.f/32768.f);
  float var=sq*(1.f/32768.f)-mu*mu;
  gst[bg*2]=mu; gst[bg*2+1]=rsqrtf(var+1e-5f);
}

// ---------------- groupnorm apply + transpose to ht[B][N][C] bf16 ----------------
__global__ void gn_apply_kernel(const float* __restrict__ x, const float* __restrict__ gw,
                                const float* __restrict__ gb, const float* __restrict__ gst,
                                ushort* __restrict__ ht){
  int nt=blockIdx.x, ct=blockIdx.y, b=blockIdx.z;
  int n0=nt*64, c0=ct*32;
  __shared__ float tile[32][65];
  __shared__ float smu[4], srs[4], sw[32], sb[32];
  int tid=threadIdx.x;
  if(tid<4){ int g=(c0>>3)+tid; smu[tid]=gst[(b*32+g)*2]; srs[tid]=gst[(b*32+g)*2+1]; }
  if(tid<32){ sw[tid]=gw[c0+tid]; sb[tid]=gb[c0+tid]; }
  __syncthreads();
  int ci=tid>>3, j0=(tid&7)*8;
  const float* xp = x + ((size_t)(b*256)+c0+ci)*4096 + n0 + j0;
  float mu=smu[ci>>3], rs=srs[ci>>3], w=sw[ci], bb=sb[ci];
  float4 va=*reinterpret_cast<const float4*>(xp);
  float4 vb=*reinterpret_cast<const float4*>(xp+4);
  tile[ci][j0+0]=(va.x-mu)*rs*w+bb; tile[ci][j0+1]=(va.y-mu)*rs*w+bb;
  tile[ci][j0+2]=(va.z-mu)*rs*w+bb; tile[ci][j0+3]=(va.w-mu)*rs*w+bb;
  tile[ci][j0+4]=(vb.x-mu)*rs*w+bb; tile[ci][j0+5]=(vb.y-mu)*rs*w+bb;
  tile[ci][j0+6]=(vb.z-mu)*rs*w+bb; tile[ci][j0+7]=(vb.w-mu)*rs*w+bb;
  __syncthreads();
  int nl=tid>>2, oct=tid&3;
  union{ ushort u[8]; uint4 v; } o;
  #pragma unroll
  for(int j=0;j<8;j++) o.u[j]=f2bf(tile[oct*8+j][nl]);
  *reinterpret_cast<uint4*>(ht + ((size_t)(b*4096)+n0+nl)*256 + c0 + oct*8) = o.v;
}

// ---------------- fused Q+K GEMM: shares the A (ht) tile ----------------
__global__ __launch_bounds__(256,2) void gemm_qk(const ushort* __restrict__ A,
         const ushort* __restrict__ Bq, const ushort* __restrict__ Bk,
         ushort* __restrict__ Dq, ushort* __restrict__ Dk,
         const float* __restrict__ bq, const float* __restrict__ bk, float qscale){
  __shared__ ushort Al[128*64];
  __shared__ ushort Bql[128*64];
  __shared__ ushort Bkl[128*64];
  int m0=blockIdx.x*128, n0=blockIdx.y*128;
  int tid=threadIdx.x, w=tid>>6, lane=tid&63, ln=lane&31, hi=lane>>5;
  f32x16 aq[2][2], ak[2][2];
  #pragma unroll
  for(int a=0;a<2;a++)
    #pragma unroll
    for(int c=0;c<2;c++)
      #pragma unroll
      for(int r=0;r<16;r++){ aq[a][c][r]=0.f; ak[a][c][r]=0.f; }
  for(int kt=0;kt<4;kt++){
    __syncthreads();
    #pragma unroll
    for(int i=0;i<4;i++){
      int idx=i*256+tid; int row=idx>>3; int chs=(idx^row)&7;
      gload16(A  + (size_t)(m0+row)*256 + kt*64 + chs*8, (char*)Al  + (i*256+w*64)*16);
    }
    #pragma unroll
    for(int i=0;i<4;i++){
      int idx=i*256+tid; int row=idx>>3; int chs=(idx^row)&7;
      gload16(Bq + (size_t)(n0+row)*256 + kt*64 + chs*8, (char*)Bql + (i*256+w*64)*16);
    }
    #pragma unroll
    for(int i=0;i<4;i++){
      int idx=i*256+tid; int row=idx>>3; int chs=(idx^row)&7;
      gload16(Bk + (size_t)(n0+row)*256 + kt*64 + chs*8, (char*)Bkl + (i*256+w*64)*16);
    }
    __syncthreads();
    #pragma unroll
    for(int kk=0;kk<4;kk++){
      short8 af[2], bqf[2], bkf[2];
      #pragma unroll
      for(int t=0;t<2;t++){
        int ra=(w>>1)*64+t*32+ln; int ca=((kk*2+hi)^ra)&7;
        af[t]=*reinterpret_cast<const short8*>(Al + ra*64 + ca*8);
        int rb=(w&1)*64+t*32+ln; int cb=((kk*2+hi)^rb)&7;
        bqf[t]=*reinterpret_cast<const short8*>(Bql + rb*64 + cb*8);
        bkf[t]=*reinterpret_cast<const short8*>(Bkl + rb*64 + cb*8);
      }
      #pragma unroll
      for(int ti=0;ti<2;ti++)
        #pragma unroll
        for(int tj=0;tj<2;tj++){
          aq[ti][tj]=__builtin_amdgcn_mfma_f32_32x32x16_bf16(af[ti],bqf[tj],aq[ti][tj],0,0,0);
          ak[ti][tj]=__builtin_amdgcn_mfma_f32_32x32x16_bf16(af[ti],bkf[tj],ak[ti][tj],0,0,0);
        }
    }
  }
  #pragma unroll
  for(int ti=0;ti<2;ti++){
    #pragma unroll
    for(int tj=0;tj<2;tj++){
      int col=n0+(w&1)*64+tj*32+ln;
      float bqc=bq[col], bkc=bk[col];
      #pragma unroll
      for(int r=0;r<16;r++){
        int row=m0+(w>>1)*64+ti*32+(r&3)+8*(r>>2)+4*hi;
        Dq[(size_t)row*256+col]=f2bf((aq[ti][tj][r]+bqc)*qscale);
        Dk[(size_t)row*256+col]=f2bf(ak[ti][tj][r]+bkc);
      }
    }
  }
}

// ---------------- V^T GEMM (wv as A-operand): D[c][tok] ----------------
__global__ __launch_bounds__(256,2) void gemm_vt(const ushort* __restrict__ A, const ushort* __restrict__ Bm,
         ushort* __restrict__ D, const float* __restrict__ bias){
  __shared__ ushort Al[128*64];
  __shared__ ushort Bl[128*64];
  int m0=blockIdx.x*128, n0=blockIdx.y*128;
  int tid=threadIdx.x, w=tid>>6, lane=tid&63, ln=lane&31, hi=lane>>5;
  f32x16 acc[2][2];
  #pragma unroll
  for(int a=0;a<2;a++)
    #pragma unroll
    for(int c=0;c<2;c++)
      #pragma unroll
      for(int r=0;r<16;r++) acc[a][c][r]=0.f;
  for(int kt=0;kt<4;kt++){
    __syncthreads();
    #pragma unroll
    for(int i=0;i<4;i++){
      int idx=i*256+tid; int row=idx>>3; int chs=(idx^row)&7;
      gload16(A + (size_t)(m0+row)*256 + kt*64 + chs*8, (char*)Al + (i*256+w*64)*16);
    }
    #pragma unroll
    for(int i=0;i<4;i++){
      int idx=i*256+tid; int row=idx>>3; int chs=(idx^row)&7;
      gload16(Bm + (size_t)(n0+row)*256 + kt*64 + chs*8, (char*)Bl + (i*256+w*64)*16);
    }
    __syncthreads();
    #pragma unroll
    for(int kk=0;kk<4;kk++){
      short8 af[2], bfr[2];
      #pragma unroll
      for(int t=0;t<2;t++){
        int ra=(w>>1)*64+t*32+ln; int ca=((kk*2+hi)^ra)&7;
        af[t]=*reinterpret_cast<const short8*>(Al + ra*64 + ca*8);
        int rb=(w&1)*64+t*32+ln; int cb=((kk*2+hi)^rb)&7;
        bfr[t]=*reinterpret_cast<const short8*>(Bl + rb*64 + cb*8);
      }
      #pragma unroll
      for(int ti=0;ti<2;ti++)
        #pragma unroll
        for(int tj=0;tj<2;tj++)
          acc[ti][tj]=__builtin_amdgcn_mfma_f32_32x32x16_bf16(af[ti],bfr[tj],acc[ti][tj],0,0,0);
    }
  }
  #pragma unroll
  for(int ti=0;ti<2;ti++){
    #pragma unroll
    for(int tj=0;tj<2;tj++){
      int col=n0+(w&1)*64+tj*32+ln;
      #pragma unroll
      for(int r=0;r<16;r++){
        int row=m0+(w>>1)*64+ti*32+(r&3)+8*(r>>2)+4*hi;
        D[(size_t)row*32768+col]=f2bf(acc[ti][tj][r]+bias[row]);
      }
    }
  }
}

// ---------------- fused flash attention + output projection + residual ----------------
// 256 blocks x 512 threads (8 waves). wave w: q-group w&3 (32 of 128 rows), K-half w>>2.
// QBLK=128: each staged K/V tile serves 128 q-rows (half the staging of QBLK=64).
// K and V both double-buffered (128KB LDS); K(t+1)/V(t+1) issued at iter TOP ->
// full-iteration prefetch windows. 3 barriers/iter. vmcnt invariant at top:
// queue=[K(t)x8, V(t)x8]; +16 issued -> K ready @ vmcnt(24), V ready @ vmcnt(16).
// K swizzle upgraded to 5-bit XOR (32 chunks/row) -> QK ds_read_b128 conflict-free.
// XCD swizzle: cid=(bid&7)*32+bid>>3 -> each XCD owns one batch (4MB K+V fits L2).
__global__ __launch_bounds__(512,2) void attn_kernel(
    const ushort* __restrict__ qb, const ushort* __restrict__ kb,
    const ushort* __restrict__ vtb, const ushort* __restrict__ wob,
    const float* __restrict__ bo, const float* __restrict__ x,
    float* __restrict__ out){
  __shared__ ushort Kl[2][64*256];     // 2 x 32KB, 5-bit XOR swizzled rows of 512B
  __shared__ ushort Vl[2][256*64];     // 2 x 32KB, 3-bit XOR swizzled rows of 128B
  __shared__ float ml[8][2][32];
  float* exch = reinterpret_cast<float*>(&Kl[0][0]);   // 64KB, used only after loop
  int tid=threadIdx.x, w=tid>>6, lane=tid&63, ln=lane&31, hi=lane>>5;
  int qg=w&3, h=w>>2;
  int bid=blockIdx.x;
  int cid=(bid&7)*32 + (bid>>3);       // XCD-affine remap (256 = 8*32, bijective)
  int b=cid>>5, nt=cid&31;
  int n0=nt*128+qg*32;
  int n=n0+ln;
  short8 qf[16];
  {
    const ushort* qrow = qb + ((size_t)(b*4096)+n)*256 + hi*8;
    #pragma unroll
    for(int kc=0;kc<16;kc++) qf[kc]=*reinterpret_cast<const short8*>(qrow+kc*16);
  }
  f32x16 oacc[8];
  #pragma unroll
  for(int i=0;i<8;i++)
    #pragma unroll
    for(int r=0;r<16;r++) oacc[i][r]=0.f;
  float M=-3.0e38f, L=0.f;
  const ushort* kbp = kb + (size_t)b*4096*256;
  const ushort* vbp = vtb + (size_t)b*4096;

  auto stageK=[&](int t1, int bi){
    #pragma unroll
    for(int i=0;i<4;i++){
      int idx=i*512+tid; int row=idx>>5, ch=idx&31;
      int chs=ch^(row&31);                       // 5-bit XOR: conflict-free reads
      gload16(kbp + (size_t)(t1*64+row)*256 + chs*8, (char*)&Kl[bi][0] + (i*512+w*64)*16);
    }
  };
  auto stageV=[&](int t1, int bi){
    #pragma unroll
    for(int i=0;i<4;i++){
      int idx=i*512+tid; int row=idx>>3; int chs=(idx^row)&7;
      gload16(vbp + (size_t)row*32768 + t1*64 + chs*8, (char*)&Vl[bi][0] + (i*512+w*64)*16);
    }
  };

  stageK(0,0); stageV(0,0);   // prologue: queue = [K0 x8, V0 x8]

  for(int t=0;t<64;t++){
    int cur=t&1;
    if(t<63){
      stageK(t+1,cur^1);                              // K(t-1) reads done at t-1 mid-barrier
      stageV(t+1,cur^1);                              // V(t-1) reads done at t-1 end-barrier
      asm volatile("s_waitcnt vmcnt(24)" ::: "memory");  // K(t) done
    } else {
      asm volatile("s_waitcnt vmcnt(8)" ::: "memory");
    }
    asm volatile("s_barrier" ::: "memory");           // K(t) visible to all
    // S^T[m][n] = K x Q (swapped): softmax over m is lane-local; log2 domain
    f32x16 s;
    #pragma unroll
    for(int r=0;r<16;r++) s[r]=0.f;
    int kr=h*32+ln;
    const ushort* klr = &Kl[cur][0] + kr*256;
    #pragma unroll
    for(int kc=0;kc<16;kc++){
      int cw=kc*2+hi; int chs=cw^(kr&31);
      short8 a=*reinterpret_cast<const short8*>(klr+chs*8);
      s=__builtin_amdgcn_mfma_f32_32x32x16_bf16(a,qf[kc],s,0,0,0);
    }
    float tmax=fmaxf(fmaxf(fmaxf(s[0],s[1]),fmaxf(s[2],s[3])),
                     fmaxf(fmaxf(s[4],s[5]),fmaxf(s[6],s[7])));
    float tmax2=fmaxf(fmaxf(fmaxf(s[8],s[9]),fmaxf(s[10],s[11])),
                      fmaxf(fmaxf(s[12],s[13]),fmaxf(s[14],s[15])));
    tmax=xmax32(fmaxf(tmax,tmax2));
    if(__any(tmax > M + 8.f)){          // defer-max: P bounded by 2^8
      float Mn=fmaxf(M,tmax);
      float sc=exp2f(M-Mn);
      L*=sc;
      #pragma unroll
      for(int i=0;i<8;i++)
        #pragma unroll
        for(int r=0;r<16;r++) oacc[i][r]*=sc;
      M=Mn;
    }
    float p[16]; float ts=0.f;
    #pragma unroll
    for(int r=0;r<16;r++){ p[r]=exp2f(s[r]-M); ts+=p[r]; }
    L+=xsum32(ts);
    // P -> B-operand frags [m=hi*8+e][n=ln]
    short8 pa[2];
    #pragma unroll
    for(int ks=0;ks<2;ks++){
      uint32_t c01=pk2t(p[ks*8+0],p[ks*8+1]);
      uint32_t c23=pk2t(p[ks*8+2],p[ks*8+3]);
      uint32_t c45=pk2t(p[ks*8+4],p[ks*8+5]);
      uint32_t c67=pk2t(p[ks*8+6],p[ks*8+7]);
      uint32_t x01=(uint32_t)__shfl_xor((int)c01,32), x23=(uint32_t)__shfl_xor((int)c23,32);
      uint32_t x45=(uint32_t)__shfl_xor((int)c45,32), x67=(uint32_t)__shfl_xor((int)c67,32);
      union{ uint32_t u[4]; short8 v; } r_;
      r_.u[0]= hi? x45:c01;
      r_.u[1]= hi? x67:c23;
      r_.u[2]= hi? c45:x01;
      r_.u[3]= hi? c67:x23;
      pa[ks]=r_.v;
    }
    if(t<63){ asm volatile("s_waitcnt vmcnt(16)" ::: "memory"); }  // V(t) done
    else    { asm volatile("s_waitcnt vmcnt(0)"  ::: "memory"); }
    asm volatile("s_barrier" ::: "memory");           // V(t) visible; also: K(t) reads done
    // O^T[c][n] += V^T x P
    #pragma unroll
    for(int ct=0;ct<8;ct++){
      int c=ct*32+ln;
      const ushort* vlr = &Vl[cur][0] + c*64;
      #pragma unroll
      for(int ks=0;ks<2;ks++){
        int cw=h*4+ks*2+hi; int chs=cw^(c&7);
        short8 a=*reinterpret_cast<const short8*>(vlr+chs*8);
        oacc[ct]=__builtin_amdgcn_mfma_f32_32x32x16_bf16(a,pa[ks],oacc[ct],0,0,0);
      }
    }
    asm volatile("s_barrier" ::: "memory");           // V(t) reads done
  }
  // -------- merge the two K-halves (wave pair w, w^4) --------
  __syncthreads();
  if(hi==0){ ml[w][0][ln]=M; ml[w][1][ln]=L; }
  __syncthreads();
  float Mp=ml[w^4][0][ln], Lp=ml[w^4][1][ln];
  float Mt=fmaxf(M,Mp);
  float fo=exp2f(M-Mt), fpp=exp2f(Mp-Mt);
  float g=fo/(fo*L+fpp*Lp);
  #pragma unroll
  for(int i=0;i<8;i++)
    #pragma unroll
    for(int r=0;r<16;r++) oacc[i][r]*=g;
  short8 obf[16];
  #pragma unroll
  for(int cb=0;cb<4;cb++){
    __syncthreads();
    float* ex=exch + w*2048;
    #pragma unroll
    for(int u=0;u<2;u++){
      int ct=cb*2+u;
      #pragma unroll
      for(int r=0;r<16;r++){
        int cl=u*32+(r&3)+8*(r>>2)+4*hi;
        ex[cl*32+ln]=oacc[ct][r];
      }
    }
    __syncthreads();
    const float* exq=exch + (w^4)*2048;
    #pragma unroll
    for(int u=0;u<2;u++){
      int ct=cb*2+u;
      #pragma unroll
      for(int r=0;r<16;r++){
        int cl=u*32+(r&3)+8*(r>>2)+4*hi;
        oacc[ct][r]+=exq[cl*32+ln];
      }
    }
    #pragma unroll
    for(int kq=0;kq<4;kq++){
      int ct=cb*2+(kq>>1); int rb=(kq&1)*8;
      uint32_t c01=pk2t(oacc[ct][rb+0],oacc[ct][rb+1]);
      uint32_t c23=pk2t(oacc[ct][rb+2],oacc[ct][rb+3]);
      uint32_t c45=pk2t(oacc[ct][rb+4],oacc[ct][rb+5]);
      uint32_t c67=pk2t(oacc[ct][rb+6],oacc[ct][rb+7]);
      uint32_t x01=(uint32_t)__shfl_xor((int)c01,32), x23=(uint32_t)__shfl_xor((int)c23,32);
      uint32_t x45=(uint32_t)__shfl_xor((int)c45,32), x67=(uint32_t)__shfl_xor((int)c67,32);
      union{ uint32_t u[4]; short8 v; } r_;
      r_.u[0]= hi? x45:c01;
      r_.u[1]= hi? x67:c23;
      r_.u[2]= hi? c45:x01;
      r_.u[3]= hi? c67:x23;
      obf[cb*4+kq]=r_.v;
    }
  }
  // -------- fused output projection + bias + residual --------
  #pragma unroll
  for(int cot=0;cot<4;cot++){
    f32x16 d;
    #pragma unroll
    for(int r=0;r<16;r++) d[r]=0.f;
    int coa=h*128+cot*32+ln;
    const ushort* wr=wob+(size_t)coa*256+hi*8;
    #pragma unroll
    for(int kbv=0;kbv<16;kbv++){
      short8 a=*reinterpret_cast<const short8*>(wr+kbv*16);
      d=__builtin_amdgcn_mfma_f32_32x32x16_bf16(a,obf[kbv],d,0,0,0);
    }
    #pragma unroll
    for(int r=0;r<16;r++){
      int co=h*128+cot*32+(r&3)+8*(r>>2)+4*hi;
      size_t oi=((size_t)(b*256)+co)*4096 + n0+ln;
      out[oi]=d[r]+bo[co]+x[oi];
    }
  }
}

extern "C" void kernel_launch(void* const* d_in, const int* in_sizes, int n_in,
                              void* d_out, int out_size, void* d_ws, size_t ws_size,
                              hipStream_t stream){
  const float* x   =(const float*)d_in[0];
  const float* gw  =(const float*)d_in[1];
  const float* gb  =(const float*)d_in[2];
  const float* wq  =(const float*)d_in[3];
  const float* bq  =(const float*)d_in[4];
  const float* wk  =(const float*)d_in[5];
  const float* bk  =(const float*)d_in[6];
  const float* wv  =(const float*)d_in[7];
  const float* bv  =(const float*)d_in[8];
  const float* wo  =(const float*)d_in[9];
  const float* bo  =(const float*)d_in[10];
  float* out=(float*)d_out;
  char* ws=(char*)d_ws;
  const size_t SZ = (size_t)32768*256*2;   // 16MB per bf16 tensor
  ushort* ht =(ushort*)(ws);
  ushort* qb =(ushort*)(ws+SZ);
  ushort* kb2=(ushort*)(ws+2*SZ);
  ushort* vtb=(ushort*)(ws+3*SZ);
  ushort* wqb=(ushort*)(ws+4*SZ);
  ushort* wkb=(ushort*)(ws+4*SZ+131072);
  ushort* wvb=(ushort*)(ws+4*SZ+262144);
  ushort* wob=(ushort*)(ws+4*SZ+393216);
  float*  gst=(float*) (ws+4*SZ+524288);
  float*  part=(float*)(ws+4*SZ+524288+2048);

  cvt_w_kernel<<<256,256,0,stream>>>(wq,wk,wv,wo,wqb,wkb,wvb,wob);
  gn_stats1_kernel<<<2048,256,0,stream>>>(x,part);
  gn_stats2_kernel<<<1,256,0,stream>>>(part,gst);
  gn_apply_kernel<<<dim3(64,8,8),256,0,stream>>>(x,gw,gb,gst,ht);
  // Q/K fused: Q scale = log2(e)/16 (exp2-domain softmax), K scale 1
  gemm_qk<<<dim3(256,2),256,0,stream>>>(ht,wqb,wkb,qb,kb2,bq,bk,0.090168439f);
  gemm_vt<<<dim3(2,256),256,0,stream>>>(wvb,ht,vtb,bv);
  attn_kernel<<<256,512,0,stream>>>(qb,kb2,vtb,wob,bo,x,out);
}